// Round 8
// baseline (1115.293 us; speedup 1.0000x reference)
//
#include <hip/hip_runtime.h>

#define NN 512
#define BATCH 256
#define T 5

typedef unsigned long long u64;
typedef unsigned u32;

#define INVL (~0ull)
#define DEADK 512ull

// u64 max via f64 max: all keys are positive f64 bit patterns (< 2^62,
// exponent never all-ones) -> IEEE order == unsigned order. 1 instr/compare.
__device__ __forceinline__ u64 fm(u64 a, u64 b) {
    return (u64)__double_as_longlong(fmax(__longlong_as_double((long long)a),
                                          __longlong_as_double((long long)b)));
}

#define DPP_FMAX64(k, ctrl) do {                                              \
    int _lo = (int)(u32)(k); int _hi = (int)((k) >> 32);                      \
    int _olo = __builtin_amdgcn_update_dpp(_lo, _lo, ctrl, 0xf, 0xf, false);  \
    int _ohi = __builtin_amdgcn_update_dpp(_hi, _hi, ctrl, 0xf, 0xf, false);  \
    u64 _o = ((u64)(u32)_ohi << 32) | (u32)_olo;                              \
    (k) = fm((k), _o);                                                        \
} while (0)

#define WAVE_FMAX64(k) do {                                                   \
    DPP_FMAX64(k, 0x111); DPP_FMAX64(k, 0x112); DPP_FMAX64(k, 0x114);         \
    DPP_FMAX64(k, 0x118); DPP_FMAX64(k, 0x142); DPP_FMAX64(k, 0x143);         \
} while (0)

__device__ __forceinline__ u64 readlane64(u64 k, int l) {
    u32 lo = (u32)__builtin_amdgcn_readlane((int)(u32)k, l);
    u32 hi = (u32)__builtin_amdgcn_readlane((int)(k >> 32), l);
    return ((u64)hi << 32) | lo;
}

// 3-level select of the alive word for column-word w
__device__ __forceinline__ u64 amsel(int w, u64 a0, u64 a1, u64 a2, u64 a3,
                                     u64 a4, u64 a5, u64 a6, u64 a7) {
    u64 x01 = (w & 1) ? a1 : a0;
    u64 x23 = (w & 1) ? a3 : a2;
    u64 x45 = (w & 1) ? a5 : a4;
    u64 x67 = (w & 1) ? a7 : a6;
    u64 y0 = (w & 2) ? x23 : x01;
    u64 y1 = (w & 2) ? x67 : x45;
    return (w & 4) ? y1 : y0;
}

// ---------------------------------------------------------------------------
// Kernel 1: per-row top-T (desc value, asc col) -> first NN*T u64 of each
// batch's out region (staged by kernel 2 before outputs land there).
// Entry format: val_bits<<32 | col.
// ---------------------------------------------------------------------------
__global__ __launch_bounds__(256) void build_top(const float* __restrict__ s,
                                                 float* __restrict__ out) {
    const int wave = threadIdx.x >> 6;
    const int lane = threadIdx.x & 63;
    const int row_g = blockIdx.x * 4 + wave;
    const int b = row_g >> 9;
    const int r = row_g & (NN - 1);
    const float* rp = s + (size_t)row_g * NN;
    u64* dst = (u64*)(out + (size_t)b * NN * NN) + (size_t)r * T;

    const float4 a  = *(const float4*)(rp + 4 * lane);
    const float4 c2 = *(const float4*)(rp + 256 + 4 * lane);

    u64 kk0 = (((u64)__float_as_uint(a.x)  + 1) << 9) | (u32)(511 - (4*lane + 0));
    u64 kk1 = (((u64)__float_as_uint(a.y)  + 1) << 9) | (u32)(511 - (4*lane + 1));
    u64 kk2 = (((u64)__float_as_uint(a.z)  + 1) << 9) | (u32)(511 - (4*lane + 2));
    u64 kk3 = (((u64)__float_as_uint(a.w)  + 1) << 9) | (u32)(511 - (4*lane + 3));
    u64 kk4 = (((u64)__float_as_uint(c2.x) + 1) << 9) | (u32)(511 - (256 + 4*lane + 0));
    u64 kk5 = (((u64)__float_as_uint(c2.y) + 1) << 9) | (u32)(511 - (256 + 4*lane + 1));
    u64 kk6 = (((u64)__float_as_uint(c2.z) + 1) << 9) | (u32)(511 - (256 + 4*lane + 2));
    u64 kk7 = (((u64)__float_as_uint(c2.w) + 1) << 9) | (u32)(511 - (256 + 4*lane + 3));

    #pragma unroll
    for (int t = 0; t < T; ++t) {
        u64 m0 = fm(kk0, kk1), m1 = fm(kk2, kk3);
        u64 m2 = fm(kk4, kk5), m3 = fm(kk6, kk7);
        m0 = fm(m0, m1); m2 = fm(m2, m3);
        u64 bk = fm(m0, m2);
        WAVE_FMAX64(bk);
        bk = readlane64(bk, 63);

        const int wcol = 511 - (int)(bk & 511);
        const u32 vb = (u32)(bk >> 9) - 1u;
        if (lane == 0) dst[t] = ((u64)vb << 32) | (u32)wcol;

        const int owner = (wcol & 255) >> 2;
        const int slot  = ((wcol >> 8) << 2) | (wcol & 3);
        if (lane == owner) {
            kk0 = (slot == 0) ? 0 : kk0;  kk1 = (slot == 1) ? 0 : kk1;
            kk2 = (slot == 2) ? 0 : kk2;  kk3 = (slot == 3) ? 0 : kk3;
            kk4 = (slot == 4) ? 0 : kk4;  kk5 = (slot == 5) ? 0 : kk5;
            kk6 = (slot == 6) ? 0 : kk6;  kk7 = (slot == 7) ? 0 : kk7;
        }
    }
}

// ---------------------------------------------------------------------------
// Kernel 2: eager greedy matching with REGISTER-RESIDENT candidate lists.
// key  = (val_bits+1)<<32 | (512-row)<<16 | col ; DEADK = row dead.
// cand = val_bits<<32 | col (build format), INVL = empty slot; 4 per row,
// sorted desc (val, asc col). Stale heads repaired in-lane, branchlessly,
// all rows in parallel. Exhausted rows (rare): cooperative HBM reload
// installing top-1 as key + top-2 as cand[0].
// ---------------------------------------------------------------------------
__global__ __launch_bounds__(64) void greedy_match(const float* __restrict__ s,
                                                   float* __restrict__ out) {
    __shared__ __align__(16) u64 lst[NN * T];   // 20 KB

    const int b = blockIdx.x;
    const int lane = threadIdx.x;
    const float* sb = s + (size_t)b * NN * NN;
    float* ob = out + (size_t)b * NN * NN;

    // ---- stage lists (NN*T u64 = 20480 B = 1280 ulonglong2) ----
    {
        const ulonglong2* src = (const ulonglong2*)ob;
        ulonglong2* dstl = (ulonglong2*)&lst[0];
        #pragma unroll
        for (int j = 0; j < 20; ++j)
            dstl[lane + 64 * j] = src[lane + 64 * j];
    }

    u64 am0 = ~0ull, am1 = ~0ull, am2 = ~0ull, am3 = ~0ull,
        am4 = ~0ull, am5 = ~0ull, am6 = ~0ull, am7 = ~0ull;

    u64 k0, k1, k2, k3, k4, k5, k6, k7;
    u64 c00, c01, c02, c03, c10, c11, c12, c13, c20, c21, c22, c23,
        c30, c31, c32, c33, c40, c41, c42, c43, c50, c51, c52, c53,
        c60, c61, c62, c63, c70, c71, c72, c73;

#define INITJ(j, KJ, C0, C1, C2, C3) do {                                     \
        const int r_ = lane + 64 * (j);                                       \
        const u64* p_ = &lst[r_ * T];                                         \
        const u64 e_ = p_[0];                                                 \
        KJ = (((e_ >> 32) + 1ull) << 32)                                      \
           | ((u64)(u32)(512 - r_) << 16) | (e_ & 511ull);                    \
        C0 = p_[1]; C1 = p_[2]; C2 = p_[3]; C3 = p_[4];                       \
    } while (0)
    INITJ(0, k0, c00, c01, c02, c03);  INITJ(1, k1, c10, c11, c12, c13);
    INITJ(2, k2, c20, c21, c22, c23);  INITJ(3, k3, c30, c31, c32, c33);
    INITJ(4, k4, c40, c41, c42, c43);  INITJ(5, k5, c50, c51, c52, c53);
    INITJ(6, k6, c60, c61, c62, c63);  INITJ(7, k7, c70, c71, c72, c73);
#undef INITJ

    #pragma unroll 1
    for (int step = 0; step < NN; ++step) {
        // ---- pop: argmax over all 512 keys (heads always valid) ----
        u64 m0 = fm(k0, k1), m1 = fm(k2, k3), m2 = fm(k4, k5), m3 = fm(k6, k7);
        m0 = fm(m0, m1); m2 = fm(m2, m3);
        u64 bk = fm(m0, m2);
        WAVE_FMAX64(bk);
        const u32 lo = (u32)__builtin_amdgcn_readlane((int)(u32)bk, 63);
        const int cstar = (int)(lo & 511u);
        const int rstar = 512 - (int)((lo >> 16) & 1023u);
        const u32 cu = (u32)cstar;

        // ---- write output row rstar (zeros + one-hot at owner lane) ----
        {
            const int ow = cstar >> 2;      // 0..127
            const int q  = cstar & 3;
            float4 o0, o1;
            o0.x = (lane == ow && q == 0) ? 1.0f : 0.0f;
            o0.y = (lane == ow && q == 1) ? 1.0f : 0.0f;
            o0.z = (lane == ow && q == 2) ? 1.0f : 0.0f;
            o0.w = (lane == ow && q == 3) ? 1.0f : 0.0f;
            o1.x = (lane == ow - 64 && q == 0) ? 1.0f : 0.0f;
            o1.y = (lane == ow - 64 && q == 1) ? 1.0f : 0.0f;
            o1.z = (lane == ow - 64 && q == 2) ? 1.0f : 0.0f;
            o1.w = (lane == ow - 64 && q == 3) ? 1.0f : 0.0f;
            float* orow = ob + ((size_t)rstar << 9);
            *(float4*)(orow + 4 * lane) = o0;
            *(float4*)(orow + 256 + 4 * lane) = o1;
        }

        // ---- kill col cstar ----
        {
            const int cw = cstar >> 6;
            const u64 nb = ~(1ull << (cstar & 63));
            am0 = (cw == 0) ? (am0 & nb) : am0;  am1 = (cw == 1) ? (am1 & nb) : am1;
            am2 = (cw == 2) ? (am2 & nb) : am2;  am3 = (cw == 3) ? (am3 & nb) : am3;
            am4 = (cw == 4) ? (am4 & nb) : am4;  am5 = (cw == 5) ? (am5 & nb) : am5;
            am6 = (cw == 6) ? (am6 & nb) : am6;  am7 = (cw == 7) ? (am7 & nb) : am7;
        }

        // ---- kill row rstar ----
        {
            const int rl = rstar & 63, rj = rstar >> 6;
            const bool mine = (lane == rl);
            k0 = (mine && rj == 0) ? DEADK : k0;  k1 = (mine && rj == 1) ? DEADK : k1;
            k2 = (mine && rj == 2) ? DEADK : k2;  k3 = (mine && rj == 3) ? DEADK : k3;
            k4 = (mine && rj == 4) ? DEADK : k4;  k5 = (mine && rj == 5) ? DEADK : k5;
            k6 = (mine && rj == 6) ? DEADK : k6;  k7 = (mine && rj == 7) ? DEADK : k7;
        }

        // ---- stale detection (DEADK=512 never matches cu in [0,511]) ----
        u32 st8 = 0;
        st8 |= ((((u32)k0) & 1023u) == cu) ? 1u   : 0u;
        st8 |= ((((u32)k1) & 1023u) == cu) ? 2u   : 0u;
        st8 |= ((((u32)k2) & 1023u) == cu) ? 4u   : 0u;
        st8 |= ((((u32)k3) & 1023u) == cu) ? 8u   : 0u;
        st8 |= ((((u32)k4) & 1023u) == cu) ? 16u  : 0u;
        st8 |= ((((u32)k5) & 1023u) == cu) ? 32u  : 0u;
        st8 |= ((((u32)k6) & 1023u) == cu) ? 64u  : 0u;
        st8 |= ((((u32)k7) & 1023u) == cu) ? 128u : 0u;

        if (__ballot(st8 != 0u)) {
            u32 exh8 = 0;
            // in-lane branchless repair of all stale rows simultaneously
#define REB(j, KJ, C0, C1, C2, C3) do {                                       \
            const bool st_ = (st8 >> (j)) & 1u;                               \
            const int g0 = (int)(C0 & 511u), g1 = (int)(C1 & 511u);           \
            const int g2 = (int)(C2 & 511u), g3 = (int)(C3 & 511u);           \
            const u64 w0 = amsel(g0 >> 6, am0,am1,am2,am3,am4,am5,am6,am7);   \
            const u64 w1 = amsel(g1 >> 6, am0,am1,am2,am3,am4,am5,am6,am7);   \
            const u64 w2 = amsel(g2 >> 6, am0,am1,am2,am3,am4,am5,am6,am7);   \
            const u64 w3 = amsel(g3 >> 6, am0,am1,am2,am3,am4,am5,am6,am7);   \
            const bool a0 = (C0 != INVL) && (((w0 >> (g0 & 63)) & 1ull) != 0);\
            const bool a1 = (C1 != INVL) && (((w1 >> (g1 & 63)) & 1ull) != 0);\
            const bool a2 = (C2 != INVL) && (((w2 >> (g2 & 63)) & 1ull) != 0);\
            const bool a3 = (C3 != INVL) && (((w3 >> (g3 & 63)) & 1ull) != 0);\
            const u64 sel = a0 ? C0 : (a1 ? C1 : (a2 ? C2 : (a3 ? C3 : INVL)));\
            const bool good = (sel != INVL);                                  \
            const u64 rowf = (u64)(u32)(512 - (lane + 64 * (j))) << 16;       \
            const u64 nk_ = sel + (1ull << 32) + rowf;                        \
            KJ = st_ ? (good ? nk_ : DEADK) : KJ;                             \
            exh8 |= (st_ && !good) ? (1u << (j)) : 0u;                        \
        } while (0)
            REB(0, k0, c00, c01, c02, c03);  REB(1, k1, c10, c11, c12, c13);
            REB(2, k2, c20, c21, c22, c23);  REB(3, k3, c30, c31, c32, c33);
            REB(4, k4, c40, c41, c42, c43);  REB(5, k5, c50, c51, c52, c53);
            REB(6, k6, c60, c61, c62, c63);  REB(7, k7, c70, c71, c72, c73);
#undef REB

            // ---- rare: exhausted rows -> cooperative HBM reload ----
            u64 mk = __ballot(exh8 != 0u);
            while (mk) {
                const int l = (int)__builtin_ctzll(mk);
                u32 lm = (u32)__builtin_amdgcn_readlane((int)exh8, l);
                mk &= mk - 1;
                while (lm) {
                    const int jj = (int)__builtin_ctz(lm);
                    lm &= lm - 1;
                    const int row = l + 64 * jj;
                    const u64 rowf = (u64)(u32)(512 - row) << 16;
                    const float* rp = sb + (size_t)row * NN;
                    const float4 fa = *(const float4*)(rp + 4 * lane);
                    const float4 fv = *(const float4*)(rp + 256 + 4 * lane);
                    const int sh = (4 * lane) & 63; const int wq = lane >> 4;
                    u64 xlo = (wq == 0) ? am0 : (wq == 1) ? am1 : (wq == 2) ? am2 : am3;
                    u64 xhi = (wq == 0) ? am4 : (wq == 1) ? am5 : (wq == 2) ? am6 : am7;
                    const u32 al8 = ((u32)(xlo >> sh) & 0xFu)
                                  | (((u32)(xhi >> sh) & 0xFu) << 4);
                    u64 e0 = (al8 & 1u)   ? ((((u64)__float_as_uint(fa.x) + 1) << 9) | (u32)(511 - (4*lane+0))) : 0;
                    u64 e1 = (al8 & 2u)   ? ((((u64)__float_as_uint(fa.y) + 1) << 9) | (u32)(511 - (4*lane+1))) : 0;
                    u64 e2 = (al8 & 4u)   ? ((((u64)__float_as_uint(fa.z) + 1) << 9) | (u32)(511 - (4*lane+2))) : 0;
                    u64 e3 = (al8 & 8u)   ? ((((u64)__float_as_uint(fa.w) + 1) << 9) | (u32)(511 - (4*lane+3))) : 0;
                    u64 e4 = (al8 & 16u)  ? ((((u64)__float_as_uint(fv.x) + 1) << 9) | (u32)(511 - (256+4*lane+0))) : 0;
                    u64 e5 = (al8 & 32u)  ? ((((u64)__float_as_uint(fv.y) + 1) << 9) | (u32)(511 - (256+4*lane+1))) : 0;
                    u64 e6 = (al8 & 64u)  ? ((((u64)__float_as_uint(fv.z) + 1) << 9) | (u32)(511 - (256+4*lane+2))) : 0;
                    u64 e7 = (al8 & 128u) ? ((((u64)__float_as_uint(fv.w) + 1) << 9) | (u32)(511 - (256+4*lane+3))) : 0;
                    u64 n0 = fm(e0, e1), n1 = fm(e2, e3);
                    u64 n2 = fm(e4, e5), n3 = fm(e6, e7);
                    n0 = fm(n0, n1); n2 = fm(n2, n3);
                    u64 bw = fm(n0, n2);
                    WAVE_FMAX64(bw);
                    bw = readlane64(bw, 63);
                    const int wc = 511 - (int)(bw & 511);
                    const u64 nk1 = ((bw >> 9) << 32) | rowf | (u32)wc;

                    // top-2: mask out winner col, re-reduce
                    e0 = ((int)(511 - (4*lane+0)) == (int)(bw & 511)) ? 0 : e0;
                    e1 = ((int)(511 - (4*lane+1)) == (int)(bw & 511)) ? 0 : e1;
                    e2 = ((int)(511 - (4*lane+2)) == (int)(bw & 511)) ? 0 : e2;
                    e3 = ((int)(511 - (4*lane+3)) == (int)(bw & 511)) ? 0 : e3;
                    e4 = ((int)(511 - (256+4*lane+0)) == (int)(bw & 511)) ? 0 : e4;
                    e5 = ((int)(511 - (256+4*lane+1)) == (int)(bw & 511)) ? 0 : e5;
                    e6 = ((int)(511 - (256+4*lane+2)) == (int)(bw & 511)) ? 0 : e6;
                    e7 = ((int)(511 - (256+4*lane+3)) == (int)(bw & 511)) ? 0 : e7;
                    n0 = fm(e0, e1); n1 = fm(e2, e3);
                    n2 = fm(e4, e5); n3 = fm(e6, e7);
                    n0 = fm(n0, n1); n2 = fm(n2, n3);
                    u64 bw2 = fm(n0, n2);
                    WAVE_FMAX64(bw2);
                    bw2 = readlane64(bw2, 63);
                    const u64 nc0 = bw2 ? ((((bw2 >> 9) - 1ull) << 32)
                                           | (u64)(u32)(511 - (int)(bw2 & 511)))
                                        : INVL;

                    // install into (lane l, slot jj)
                    const bool mine = (lane == l);
#define INST(j, KJ, C0, C1, C2, C3) do {                                      \
                    const bool h_ = mine && (jj == (j));                      \
                    KJ = h_ ? nk1 : KJ;                                       \
                    C0 = h_ ? nc0 : C0;  C1 = h_ ? INVL : C1;                 \
                    C2 = h_ ? INVL : C2; C3 = h_ ? INVL : C3;                 \
                } while (0)
                    INST(0, k0, c00, c01, c02, c03);  INST(1, k1, c10, c11, c12, c13);
                    INST(2, k2, c20, c21, c22, c23);  INST(3, k3, c30, c31, c32, c33);
                    INST(4, k4, c40, c41, c42, c43);  INST(5, k5, c50, c51, c52, c53);
                    INST(6, k6, c60, c61, c62, c63);  INST(7, k7, c70, c71, c72, c73);
#undef INST
                }
            }
        }
    }
}

extern "C" void kernel_launch(void* const* d_in, const int* in_sizes, int n_in,
                              void* d_out, int out_size, void* d_ws, size_t ws_size,
                              hipStream_t stream) {
    const float* s = (const float*)d_in[0];
    float* out = (float*)d_out;

    build_top<<<dim3(BATCH * NN / 4), dim3(256), 0, stream>>>(s, out);
    greedy_match<<<dim3(BATCH), dim3(64), 0, stream>>>(s, out);
}

// Round 9
// 567.525 us; speedup vs baseline: 1.9652x; 1.9652x over previous
//
#include <hip/hip_runtime.h>

#define NN 512
#define BATCH 256
#define T 8

typedef unsigned long long u64;
typedef unsigned u32;

#define DEADK 512ull

// u64 max via f64 max: all keys are positive f64 bit patterns (< 2^62,
// exponent never all-ones) -> IEEE order == unsigned order. 1 instr/compare.
__device__ __forceinline__ u64 fm(u64 a, u64 b) {
    return (u64)__double_as_longlong(fmax(__longlong_as_double((long long)a),
                                          __longlong_as_double((long long)b)));
}

#define DPP_FMAX64(k, ctrl) do {                                              \
    int _lo = (int)(u32)(k); int _hi = (int)((k) >> 32);                      \
    int _olo = __builtin_amdgcn_update_dpp(_lo, _lo, ctrl, 0xf, 0xf, false);  \
    int _ohi = __builtin_amdgcn_update_dpp(_hi, _hi, ctrl, 0xf, 0xf, false);  \
    u64 _o = ((u64)(u32)_ohi << 32) | (u32)_olo;                              \
    (k) = fm((k), _o);                                                        \
} while (0)

#define WAVE_FMAX64(k) do {                                                   \
    DPP_FMAX64(k, 0x111); DPP_FMAX64(k, 0x112); DPP_FMAX64(k, 0x114);         \
    DPP_FMAX64(k, 0x118); DPP_FMAX64(k, 0x142); DPP_FMAX64(k, 0x143);         \
} while (0)

__device__ __forceinline__ u64 readlane64(u64 k, int l) {
    u32 lo = (u32)__builtin_amdgcn_readlane((int)(u32)k, l);
    u32 hi = (u32)__builtin_amdgcn_readlane((int)(k >> 32), l);
    return ((u64)hi << 32) | lo;
}

// 3-level select of the alive word for column-word w
__device__ __forceinline__ u64 amsel(int w, u64 a0, u64 a1, u64 a2, u64 a3,
                                     u64 a4, u64 a5, u64 a6, u64 a7) {
    u64 x01 = (w & 1) ? a1 : a0;
    u64 x23 = (w & 1) ? a3 : a2;
    u64 x45 = (w & 1) ? a5 : a4;
    u64 x67 = (w & 1) ? a7 : a6;
    u64 y0 = (w & 2) ? x23 : x01;
    u64 y1 = (w & 2) ? x67 : x45;
    return (w & 4) ? y1 : y0;
}

// ---------------------------------------------------------------------------
// Kernel 1: per-row top-T (desc value, asc col) -> first NN*T u64 of each
// batch's out region (staged by kernel 2 before outputs land there).
// Entry format: val_bits<<32 | col.   (proven)
// ---------------------------------------------------------------------------
__global__ __launch_bounds__(256) void build_top(const float* __restrict__ s,
                                                 float* __restrict__ out) {
    const int wave = threadIdx.x >> 6;
    const int lane = threadIdx.x & 63;
    const int row_g = blockIdx.x * 4 + wave;
    const int b = row_g >> 9;
    const int r = row_g & (NN - 1);
    const float* rp = s + (size_t)row_g * NN;
    u64* dst = (u64*)(out + (size_t)b * NN * NN) + (size_t)r * T;

    const float4 a  = *(const float4*)(rp + 4 * lane);
    const float4 c2 = *(const float4*)(rp + 256 + 4 * lane);

    u64 kk0 = (((u64)__float_as_uint(a.x)  + 1) << 9) | (u32)(511 - (4*lane + 0));
    u64 kk1 = (((u64)__float_as_uint(a.y)  + 1) << 9) | (u32)(511 - (4*lane + 1));
    u64 kk2 = (((u64)__float_as_uint(a.z)  + 1) << 9) | (u32)(511 - (4*lane + 2));
    u64 kk3 = (((u64)__float_as_uint(a.w)  + 1) << 9) | (u32)(511 - (4*lane + 3));
    u64 kk4 = (((u64)__float_as_uint(c2.x) + 1) << 9) | (u32)(511 - (256 + 4*lane + 0));
    u64 kk5 = (((u64)__float_as_uint(c2.y) + 1) << 9) | (u32)(511 - (256 + 4*lane + 1));
    u64 kk6 = (((u64)__float_as_uint(c2.z) + 1) << 9) | (u32)(511 - (256 + 4*lane + 2));
    u64 kk7 = (((u64)__float_as_uint(c2.w) + 1) << 9) | (u32)(511 - (256 + 4*lane + 3));

    #pragma unroll
    for (int t = 0; t < T; ++t) {
        u64 m0 = fm(kk0, kk1), m1 = fm(kk2, kk3);
        u64 m2 = fm(kk4, kk5), m3 = fm(kk6, kk7);
        m0 = fm(m0, m1); m2 = fm(m2, m3);
        u64 bk = fm(m0, m2);
        WAVE_FMAX64(bk);
        bk = readlane64(bk, 63);

        const int wcol = 511 - (int)(bk & 511);
        const u32 vb = (u32)(bk >> 9) - 1u;
        if (lane == 0) dst[t] = ((u64)vb << 32) | (u32)wcol;

        const int owner = (wcol & 255) >> 2;
        const int slot  = ((wcol >> 8) << 2) | (wcol & 3);
        if (lane == owner) {
            kk0 = (slot == 0) ? 0 : kk0;  kk1 = (slot == 1) ? 0 : kk1;
            kk2 = (slot == 2) ? 0 : kk2;  kk3 = (slot == 3) ? 0 : kk3;
            kk4 = (slot == 4) ? 0 : kk4;  kk5 = (slot == 5) ? 0 : kk5;
            kk6 = (slot == 6) ? 0 : kk6;  kk7 = (slot == 7) ? 0 : kk7;
        }
    }
}

// ---------------------------------------------------------------------------
// Kernel 2: MULTI-ACCEPT eager greedy matching, one wave per batch element.
// key = (val_bits+1)<<32 | (512-row)<<16 | col ; DEADK = row dead.
// Invariant: at round start every live head is valid (col alive) and equals
// the row's max over alive cols -> the argmax IS the next greedy pick.
// Multi-accept exactness: heads have distinct rows, so key prefixes
// (val,512-row) are strictly ordered. Accepting bk1 only changes heads whose
// col == col(bk1); their repaired prefix can only shrink (or stay equal with
// a larger col, still < bk2's prefix). Hence bk2 (extracted after killing
// row(bk1)) is the exact next pick iff live and col(bk2) != col(bk1);
// inductively bk3, bk4 with pairwise-new cols. Stop the prefix at the first
// violation; repairs happen once per round, after the prefix.
// ---------------------------------------------------------------------------
__global__ __launch_bounds__(64) void greedy_match(const float* __restrict__ s,
                                                   float* __restrict__ out) {
    __shared__ __align__(16) u64 lst[NN][T];   // 32 KB

    const int b = blockIdx.x;
    const int lane = threadIdx.x;
    const float* sb = s + (size_t)b * NN * NN;
    float* ob = out + (size_t)b * NN * NN;

    // ---- stage candidate lists from out-region into LDS ----
    {
        const ulonglong2* src = (const ulonglong2*)ob;
        ulonglong2* dstl = (ulonglong2*)&lst[0][0];
        #pragma unroll
        for (int j = 0; j < 32; ++j)
            dstl[lane + 64 * j] = src[lane + 64 * j];
    }

    u64 am0 = ~0ull, am1 = ~0ull, am2 = ~0ull, am3 = ~0ull,
        am4 = ~0ull, am5 = ~0ull, am6 = ~0ull, am7 = ~0ull;

    u64 k0, k1, k2, k3, k4, k5, k6, k7;
#define INITK(j, KJ) do {                                                     \
        const int r_ = lane + 64 * (j);                                       \
        const u64 e_ = lst[r_][0];                                            \
        KJ = (((e_ >> 32) + 1ull) << 32)                                      \
           | ((u64)(u32)(512 - r_) << 16) | (e_ & 511ull);                    \
    } while (0)
    INITK(0, k0); INITK(1, k1); INITK(2, k2); INITK(3, k3);
    INITK(4, k4); INITK(5, k5); INITK(6, k6); INITK(7, k7);
#undef INITK

// argmax over all 512 keys -> low 32 bits on all lanes (wave-uniform)
#define EXTRACT(LO) do {                                                      \
        u64 x0 = fm(k0, k1), x1 = fm(k2, k3);                                 \
        u64 x2 = fm(k4, k5), x3 = fm(k6, k7);                                 \
        x0 = fm(x0, x1); x2 = fm(x2, x3);                                     \
        u64 bx = fm(x0, x2);                                                  \
        WAVE_FMAX64(bx);                                                      \
        LO = (u32)__builtin_amdgcn_readlane((int)(u32)bx, 63);                \
    } while (0)

// accept match (RS, CS): one-hot output row, kill col in am, kill row in keys
#define ACCEPT(RS, CS) do {                                                   \
        float4 o0, o1;                                                        \
        o0.x = (4 * lane + 0 == (CS)) ? 1.0f : 0.0f;                          \
        o0.y = (4 * lane + 1 == (CS)) ? 1.0f : 0.0f;                          \
        o0.z = (4 * lane + 2 == (CS)) ? 1.0f : 0.0f;                          \
        o0.w = (4 * lane + 3 == (CS)) ? 1.0f : 0.0f;                          \
        o1.x = (256 + 4 * lane + 0 == (CS)) ? 1.0f : 0.0f;                    \
        o1.y = (256 + 4 * lane + 1 == (CS)) ? 1.0f : 0.0f;                    \
        o1.z = (256 + 4 * lane + 2 == (CS)) ? 1.0f : 0.0f;                    \
        o1.w = (256 + 4 * lane + 3 == (CS)) ? 1.0f : 0.0f;                    \
        float* orow_ = ob + ((size_t)(RS) << 9);                              \
        *(float4*)(orow_ + 4 * lane) = o0;                                    \
        *(float4*)(orow_ + 256 + 4 * lane) = o1;                              \
        const int cw_ = (CS) >> 6;                                            \
        const u64 nb_ = ~(1ull << ((CS) & 63));                               \
        am0 = (cw_ == 0) ? (am0 & nb_) : am0;                                 \
        am1 = (cw_ == 1) ? (am1 & nb_) : am1;                                 \
        am2 = (cw_ == 2) ? (am2 & nb_) : am2;                                 \
        am3 = (cw_ == 3) ? (am3 & nb_) : am3;                                 \
        am4 = (cw_ == 4) ? (am4 & nb_) : am4;                                 \
        am5 = (cw_ == 5) ? (am5 & nb_) : am5;                                 \
        am6 = (cw_ == 6) ? (am6 & nb_) : am6;                                 \
        am7 = (cw_ == 7) ? (am7 & nb_) : am7;                                 \
        const int rl_ = (RS) & 63, rj_ = (RS) >> 6;                           \
        const bool mine_ = (lane == rl_);                                     \
        k0 = (mine_ && rj_ == 0) ? DEADK : k0;                                \
        k1 = (mine_ && rj_ == 1) ? DEADK : k1;                                \
        k2 = (mine_ && rj_ == 2) ? DEADK : k2;                                \
        k3 = (mine_ && rj_ == 3) ? DEADK : k3;                                \
        k4 = (mine_ && rj_ == 4) ? DEADK : k4;                                \
        k5 = (mine_ && rj_ == 5) ? DEADK : k5;                                \
        k6 = (mine_ && rj_ == 6) ? DEADK : k6;                                \
        k7 = (mine_ && rj_ == 7) ? DEADK : k7;                                \
    } while (0)

    int done = 0;
    #pragma unroll 1
    for (;;) {
        // ---- accept prefix of top-4 (pairwise-distinct cols, live) ----
        u32 cA, cB = 0xFFFFu, cC = 0xFFFFu, cD = 0xFFFFu;
        {
            u32 lo1; EXTRACT(lo1);
            const int c1 = (int)(lo1 & 511u);
            const int r1 = 512 - (int)((lo1 >> 16) & 1023u);
            ACCEPT(r1, c1); ++done;
            cA = (u32)c1;

            u32 lo2; EXTRACT(lo2);
            if (lo2 >= 0x10000u) {
                const int c2 = (int)(lo2 & 511u);
                if ((u32)c2 != cA) {
                    const int r2 = 512 - (int)((lo2 >> 16) & 1023u);
                    ACCEPT(r2, c2); ++done;
                    cB = (u32)c2;

                    u32 lo3; EXTRACT(lo3);
                    if (lo3 >= 0x10000u) {
                        const int c3 = (int)(lo3 & 511u);
                        if ((u32)c3 != cA && (u32)c3 != cB) {
                            const int r3 = 512 - (int)((lo3 >> 16) & 1023u);
                            ACCEPT(r3, c3); ++done;
                            cC = (u32)c3;

                            u32 lo4; EXTRACT(lo4);
                            if (lo4 >= 0x10000u) {
                                const int c4 = (int)(lo4 & 511u);
                                if ((u32)c4 != cA && (u32)c4 != cB && (u32)c4 != cC) {
                                    const int r4 = 512 - (int)((lo4 >> 16) & 1023u);
                                    ACCEPT(r4, c4); ++done;
                                    cD = (u32)c4;
                                }
                            }
                        }
                    }
                }
            }
        }

        // ---- stale detection vs this round's accepted cols ----
        // dead keys have col field 512, never equal to cA..cD (<=511 or 0xFFFF)
        u32 st8 = 0;
#define DET(j, KJ) do {                                                       \
        const u32 ck_ = ((u32)(KJ)) & 1023u;                                  \
        const bool h_ = (ck_ == cA) | (ck_ == cB) | (ck_ == cC) | (ck_ == cD);\
        st8 |= h_ ? (1u << (j)) : 0u;                                         \
    } while (0)
        DET(0, k0); DET(1, k1); DET(2, k2); DET(3, k3);
        DET(4, k4); DET(5, k5); DET(6, k6); DET(7, k7);
#undef DET

        if (__ballot(st8 != 0u)) {
            u64 mk = __ballot(st8 != 0u);
            while (mk) {
                const int l = (int)__builtin_ctzll(mk);
                u32 lm = (u32)__builtin_amdgcn_readlane((int)st8, l);
                mk &= mk - 1;
                while (lm) {
                    const int jj = (int)__builtin_ctz(lm);
                    lm &= lm - 1;
                    const int row = l + 64 * jj;
                    const u64 rowf = (u64)(u32)(512 - row) << 16;

                    // cooperative probe: lanes 0..7 hold the row's 8 entries
                    const u64 e = lst[row][lane & 7];
                    const int c = (int)(e & 511u);
                    const u64 w = amsel(c >> 6, am0, am1, am2, am3, am4, am5, am6, am7);
                    const bool al = ((w >> (c & 63)) & 1ull) != 0ull;
                    const u64 mask = __ballot(al) & 0xFFull;

                    u64 nk;
                    if (mask) {
                        const int idx = (int)__builtin_ctzll(mask);
                        const u64 es = readlane64(e, idx);
                        nk = (((es >> 32) + 1ull) << 32) | rowf | (es & 511ull);
                    } else {
                        // cold: cooperative HBM reload, top-1 among alive cols
                        const float* rp = sb + (size_t)row * NN;
                        const float4 fa = *(const float4*)(rp + 4 * lane);
                        const float4 fv = *(const float4*)(rp + 256 + 4 * lane);
                        const int sh = (4 * lane) & 63; const int wq = lane >> 4;
                        u64 xlo = (wq == 0) ? am0 : (wq == 1) ? am1 : (wq == 2) ? am2 : am3;
                        u64 xhi = (wq == 0) ? am4 : (wq == 1) ? am5 : (wq == 2) ? am6 : am7;
                        const u32 al8 = ((u32)(xlo >> sh) & 0xFu)
                                      | (((u32)(xhi >> sh) & 0xFu) << 4);
                        u64 e0 = (al8 & 1u)   ? ((((u64)__float_as_uint(fa.x) + 1) << 9) | (u32)(511 - (4*lane+0))) : 0;
                        u64 e1 = (al8 & 2u)   ? ((((u64)__float_as_uint(fa.y) + 1) << 9) | (u32)(511 - (4*lane+1))) : 0;
                        u64 e2 = (al8 & 4u)   ? ((((u64)__float_as_uint(fa.z) + 1) << 9) | (u32)(511 - (4*lane+2))) : 0;
                        u64 e3 = (al8 & 8u)   ? ((((u64)__float_as_uint(fa.w) + 1) << 9) | (u32)(511 - (4*lane+3))) : 0;
                        u64 e4 = (al8 & 16u)  ? ((((u64)__float_as_uint(fv.x) + 1) << 9) | (u32)(511 - (256+4*lane+0))) : 0;
                        u64 e5 = (al8 & 32u)  ? ((((u64)__float_as_uint(fv.y) + 1) << 9) | (u32)(511 - (256+4*lane+1))) : 0;
                        u64 e6 = (al8 & 64u)  ? ((((u64)__float_as_uint(fv.z) + 1) << 9) | (u32)(511 - (256+4*lane+2))) : 0;
                        u64 e7 = (al8 & 128u) ? ((((u64)__float_as_uint(fv.w) + 1) << 9) | (u32)(511 - (256+4*lane+3))) : 0;
                        u64 n0 = fm(e0, e1), n1 = fm(e2, e3);
                        u64 n2 = fm(e4, e5), n3 = fm(e6, e7);
                        n0 = fm(n0, n1); n2 = fm(n2, n3);
                        u64 bw = fm(n0, n2);
                        WAVE_FMAX64(bw);
                        bw = readlane64(bw, 63);
                        const int wc = 511 - (int)(bw & 511);
                        nk = ((bw >> 9) << 32) | rowf | (u32)wc;
                    }

                    // write nk into (lane l, slot jj)
                    const bool mine = (lane == l);
                    k0 = (mine && jj == 0) ? nk : k0;  k1 = (mine && jj == 1) ? nk : k1;
                    k2 = (mine && jj == 2) ? nk : k2;  k3 = (mine && jj == 3) ? nk : k3;
                    k4 = (mine && jj == 4) ? nk : k4;  k5 = (mine && jj == 5) ? nk : k5;
                    k6 = (mine && jj == 6) ? nk : k6;  k7 = (mine && jj == 7) ? nk : k7;
                }
            }
        }

        if (done >= NN) break;
    }
}

extern "C" void kernel_launch(void* const* d_in, const int* in_sizes, int n_in,
                              void* d_out, int out_size, void* d_ws, size_t ws_size,
                              hipStream_t stream) {
    const float* s = (const float*)d_in[0];
    float* out = (float*)d_out;

    build_top<<<dim3(BATCH * NN / 4), dim3(256), 0, stream>>>(s, out);
    greedy_match<<<dim3(BATCH), dim3(64), 0, stream>>>(s, out);
}

// Round 10
// 564.274 us; speedup vs baseline: 1.9765x; 1.0058x over previous
//
#include <hip/hip_runtime.h>

#define NN 512
#define BATCH 256
#define T 8

typedef unsigned long long u64;
typedef unsigned u32;

#define DEADK 512ull

// u64 max via f64 max: all keys are positive f64 bit patterns (< 2^62,
// exponent never all-ones) -> IEEE order == unsigned order. 1 instr/compare.
__device__ __forceinline__ u64 fm(u64 a, u64 b) {
    return (u64)__double_as_longlong(fmax(__longlong_as_double((long long)a),
                                          __longlong_as_double((long long)b)));
}

#define DPP_FMAX64(k, ctrl) do {                                              \
    int _lo = (int)(u32)(k); int _hi = (int)((k) >> 32);                      \
    int _olo = __builtin_amdgcn_update_dpp(_lo, _lo, ctrl, 0xf, 0xf, false);  \
    int _ohi = __builtin_amdgcn_update_dpp(_hi, _hi, ctrl, 0xf, 0xf, false);  \
    u64 _o = ((u64)(u32)_ohi << 32) | (u32)_olo;                              \
    (k) = fm((k), _o);                                                        \
} while (0)

#define WAVE_FMAX64(k) do {                                                   \
    DPP_FMAX64(k, 0x111); DPP_FMAX64(k, 0x112); DPP_FMAX64(k, 0x114);         \
    DPP_FMAX64(k, 0x118); DPP_FMAX64(k, 0x142); DPP_FMAX64(k, 0x143);         \
} while (0)

// 32-bit unsigned DPP max (v_max_u32), result valid in lane 63
#define DPP_MAXU32(x, ctrl) do {                                              \
    u32 _o = (u32)__builtin_amdgcn_update_dpp((int)(x), (int)(x),             \
                                              ctrl, 0xf, 0xf, false);         \
    (x) = ((x) > _o) ? (x) : _o;                                              \
} while (0)

#define WAVE_MAXU32(x) do {                                                   \
    DPP_MAXU32(x, 0x111); DPP_MAXU32(x, 0x112); DPP_MAXU32(x, 0x114);         \
    DPP_MAXU32(x, 0x118); DPP_MAXU32(x, 0x142); DPP_MAXU32(x, 0x143);         \
} while (0)

__device__ __forceinline__ u64 readlane64(u64 k, int l) {
    u32 lo = (u32)__builtin_amdgcn_readlane((int)(u32)k, l);
    u32 hi = (u32)__builtin_amdgcn_readlane((int)(k >> 32), l);
    return ((u64)hi << 32) | lo;
}

// 3-level select of the alive word for column-word w
__device__ __forceinline__ u64 amsel(int w, u64 a0, u64 a1, u64 a2, u64 a3,
                                     u64 a4, u64 a5, u64 a6, u64 a7) {
    u64 x01 = (w & 1) ? a1 : a0;
    u64 x23 = (w & 1) ? a3 : a2;
    u64 x45 = (w & 1) ? a5 : a4;
    u64 x67 = (w & 1) ? a7 : a6;
    u64 y0 = (w & 2) ? x23 : x01;
    u64 y1 = (w & 2) ? x67 : x45;
    return (w & 4) ? y1 : y0;
}

// ---------------------------------------------------------------------------
// Kernel 1: per-row top-T (desc value, asc col) -> first NN*T u64 of each
// batch's out region (staged by kernel 2 before outputs land there).
// Entry format: val_bits<<32 | col.   (proven)
// ---------------------------------------------------------------------------
__global__ __launch_bounds__(256) void build_top(const float* __restrict__ s,
                                                 float* __restrict__ out) {
    const int wave = threadIdx.x >> 6;
    const int lane = threadIdx.x & 63;
    const int row_g = blockIdx.x * 4 + wave;
    const int b = row_g >> 9;
    const int r = row_g & (NN - 1);
    const float* rp = s + (size_t)row_g * NN;
    u64* dst = (u64*)(out + (size_t)b * NN * NN) + (size_t)r * T;

    const float4 a  = *(const float4*)(rp + 4 * lane);
    const float4 c2 = *(const float4*)(rp + 256 + 4 * lane);

    u64 kk0 = (((u64)__float_as_uint(a.x)  + 1) << 9) | (u32)(511 - (4*lane + 0));
    u64 kk1 = (((u64)__float_as_uint(a.y)  + 1) << 9) | (u32)(511 - (4*lane + 1));
    u64 kk2 = (((u64)__float_as_uint(a.z)  + 1) << 9) | (u32)(511 - (4*lane + 2));
    u64 kk3 = (((u64)__float_as_uint(a.w)  + 1) << 9) | (u32)(511 - (4*lane + 3));
    u64 kk4 = (((u64)__float_as_uint(c2.x) + 1) << 9) | (u32)(511 - (256 + 4*lane + 0));
    u64 kk5 = (((u64)__float_as_uint(c2.y) + 1) << 9) | (u32)(511 - (256 + 4*lane + 1));
    u64 kk6 = (((u64)__float_as_uint(c2.z) + 1) << 9) | (u32)(511 - (256 + 4*lane + 2));
    u64 kk7 = (((u64)__float_as_uint(c2.w) + 1) << 9) | (u32)(511 - (256 + 4*lane + 3));

    #pragma unroll
    for (int t = 0; t < T; ++t) {
        u64 m0 = fm(kk0, kk1), m1 = fm(kk2, kk3);
        u64 m2 = fm(kk4, kk5), m3 = fm(kk6, kk7);
        m0 = fm(m0, m1); m2 = fm(m2, m3);
        u64 bk = fm(m0, m2);
        WAVE_FMAX64(bk);
        bk = readlane64(bk, 63);

        const int wcol = 511 - (int)(bk & 511);
        const u32 vb = (u32)(bk >> 9) - 1u;
        if (lane == 0) dst[t] = ((u64)vb << 32) | (u32)wcol;

        const int owner = (wcol & 255) >> 2;
        const int slot  = ((wcol >> 8) << 2) | (wcol & 3);
        if (lane == owner) {
            kk0 = (slot == 0) ? 0 : kk0;  kk1 = (slot == 1) ? 0 : kk1;
            kk2 = (slot == 2) ? 0 : kk2;  kk3 = (slot == 3) ? 0 : kk3;
            kk4 = (slot == 4) ? 0 : kk4;  kk5 = (slot == 5) ? 0 : kk5;
            kk6 = (slot == 6) ? 0 : kk6;  kk7 = (slot == 7) ? 0 : kk7;
        }
    }
}

// ---------------------------------------------------------------------------
// Kernel 2: lazy greedy matching, slim pop.
// key = (val_bits+1)<<32 | (512-row)<<16 | col ; DEADK = row dead.
// Pop: local u64 tree (exact in-lane tie-break) -> 32-bit wave val-max ->
// single-candidate fast path (1 readlane) / rare multi-tie exact u64 reduce.
// Accept effects are branchless & idempotent: output rows are rewritten in
// full at the true accept, so stale pops may harmlessly write garbage rows;
// col-kill is predicated on validity; key write merges DEADK/fixed-head.
// Fix (stale head): wave-cooperative probe of the row's 8-entry LDS list
// (prefetched before the branch), rare cold HBM reload.
// ---------------------------------------------------------------------------
__global__ __launch_bounds__(64) void greedy_match(const float* __restrict__ s,
                                                   float* __restrict__ out) {
    __shared__ __align__(16) u64 lst[NN][T];   // 32 KB

    const int b = blockIdx.x;
    const int lane = threadIdx.x;
    const float* sb = s + (size_t)b * NN * NN;
    float* ob = out + (size_t)b * NN * NN;

    // ---- stage candidate lists from out-region into LDS ----
    {
        const ulonglong2* src = (const ulonglong2*)ob;
        ulonglong2* dstl = (ulonglong2*)&lst[0][0];
        #pragma unroll
        for (int j = 0; j < 32; ++j)
            dstl[lane + 64 * j] = src[lane + 64 * j];
    }

    u64 am0 = ~0ull, am1 = ~0ull, am2 = ~0ull, am3 = ~0ull,
        am4 = ~0ull, am5 = ~0ull, am6 = ~0ull, am7 = ~0ull;

    u64 k0, k1, k2, k3, k4, k5, k6, k7;
#define INITK(j, KJ) do {                                                     \
        const int r_ = lane + 64 * (j);                                       \
        const u64 e_ = lst[r_][0];                                            \
        KJ = (((e_ >> 32) + 1ull) << 32)                                      \
           | ((u64)(u32)(512 - r_) << 16) | (e_ & 511ull);                    \
    } while (0)
    INITK(0, k0); INITK(1, k1); INITK(2, k2); INITK(3, k3);
    INITK(4, k4); INITK(5, k5); INITK(6, k6); INITK(7, k7);
#undef INITK

    const float4 z4 = {0.0f, 0.0f, 0.0f, 0.0f};
    int done = 0;

    for (;;) {
        // ---- local exact argmax over this lane's 8 keys ----
        u64 m0 = fm(k0, k1), m1 = fm(k2, k3), m2 = fm(k4, k5), m3 = fm(k6, k7);
        m0 = fm(m0, m1); m2 = fm(m2, m3);
        const u64 lm = fm(m0, m2);

        // ---- 32-bit wave max over val fields ----
        u32 x = (u32)(lm >> 32);
        WAVE_MAXU32(x);
        const u32 vmax = (u32)__builtin_amdgcn_readlane((int)x, 63);
        const u64 tie = __ballot((u32)(lm >> 32) == vmax);

        u32 lo;
        if (__builtin_popcountll(tie) == 1) {
            // fast path: unique winning lane; its local key is exact
            lo = (u32)__builtin_amdgcn_readlane((int)(u32)lm,
                                                (int)__builtin_ctzll(tie));
        } else {
            // rare: cross-lane val tie -> exact u64 reduce
            u64 bk = lm;
            WAVE_FMAX64(bk);
            lo = (u32)__builtin_amdgcn_readlane((int)(u32)bk, 63);
        }
        const int cstar = (int)(lo & 511u);
        const int rstar = 512 - (int)((lo >> 16) & 1023u);

        // ---- speculative probe prefetch (used only if stale) ----
        const u64 e = lst[rstar][lane & 7];

        // ---- validity (wave-uniform) ----
        const int cw = cstar >> 6;
        const u64 aw = amsel(cw, am0, am1, am2, am3, am4, am5, am6, am7);
        const bool valid = ((aw >> (cstar & 63)) & 1ull) != 0ull;

        // ---- idempotent output write (true accept rewrites the row) ----
        float* orow = ob + ((size_t)rstar << 9);
        *(float4*)(orow + 4 * lane) = z4;
        *(float4*)(orow + 256 + 4 * lane) = z4;
        if (lane == ((cstar & 255) >> 2)) orow[cstar] = 1.0f;

        // ---- col kill, predicated on valid ----
        {
            const u64 kb = valid ? (1ull << (cstar & 63)) : 0ull;
            am0 = (cw == 0) ? (am0 & ~kb) : am0;  am1 = (cw == 1) ? (am1 & ~kb) : am1;
            am2 = (cw == 2) ? (am2 & ~kb) : am2;  am3 = (cw == 3) ? (am3 & ~kb) : am3;
            am4 = (cw == 4) ? (am4 & ~kb) : am4;  am5 = (cw == 5) ? (am5 & ~kb) : am5;
            am6 = (cw == 6) ? (am6 & ~kb) : am6;  am7 = (cw == 7) ? (am7 & ~kb) : am7;
        }

        // ---- new key for row rstar: DEADK if accepted, else fixed head ----
        u64 nk = DEADK;
        if (!valid) {
            const int c = (int)(e & 511u);
            const u64 w = amsel(c >> 6, am0, am1, am2, am3, am4, am5, am6, am7);
            const bool al = ((w >> (c & 63)) & 1ull) != 0ull;
            const u64 mask = __ballot(al) & 0xFFull;
            const u64 rowf = (u64)(u32)(512 - rstar) << 16;
            if (mask) {
                const u64 es = readlane64(e, (int)__builtin_ctzll(mask));
                nk = (((es >> 32) + 1ull) << 32) | rowf | (es & 511ull);
            } else {
                // cold: cooperative HBM reload, top-1 among alive cols
                const float* rp = sb + (size_t)rstar * NN;
                const float4 fa = *(const float4*)(rp + 4 * lane);
                const float4 fv = *(const float4*)(rp + 256 + 4 * lane);
                const int sh = (4 * lane) & 63; const int wq = lane >> 4;
                u64 xlo = (wq == 0) ? am0 : (wq == 1) ? am1 : (wq == 2) ? am2 : am3;
                u64 xhi = (wq == 0) ? am4 : (wq == 1) ? am5 : (wq == 2) ? am6 : am7;
                const u32 al8 = ((u32)(xlo >> sh) & 0xFu)
                              | (((u32)(xhi >> sh) & 0xFu) << 4);
                u64 e0 = (al8 & 1u)   ? ((((u64)__float_as_uint(fa.x) + 1) << 9) | (u32)(511 - (4*lane+0))) : 0;
                u64 e1 = (al8 & 2u)   ? ((((u64)__float_as_uint(fa.y) + 1) << 9) | (u32)(511 - (4*lane+1))) : 0;
                u64 e2 = (al8 & 4u)   ? ((((u64)__float_as_uint(fa.z) + 1) << 9) | (u32)(511 - (4*lane+2))) : 0;
                u64 e3 = (al8 & 8u)   ? ((((u64)__float_as_uint(fa.w) + 1) << 9) | (u32)(511 - (4*lane+3))) : 0;
                u64 e4 = (al8 & 16u)  ? ((((u64)__float_as_uint(fv.x) + 1) << 9) | (u32)(511 - (256+4*lane+0))) : 0;
                u64 e5 = (al8 & 32u)  ? ((((u64)__float_as_uint(fv.y) + 1) << 9) | (u32)(511 - (256+4*lane+1))) : 0;
                u64 e6 = (al8 & 64u)  ? ((((u64)__float_as_uint(fv.z) + 1) << 9) | (u32)(511 - (256+4*lane+2))) : 0;
                u64 e7 = (al8 & 128u) ? ((((u64)__float_as_uint(fv.w) + 1) << 9) | (u32)(511 - (256+4*lane+3))) : 0;
                u64 n0 = fm(e0, e1), n1 = fm(e2, e3);
                u64 n2 = fm(e4, e5), n3 = fm(e6, e7);
                n0 = fm(n0, n1); n2 = fm(n2, n3);
                u64 bw = fm(n0, n2);
                WAVE_FMAX64(bw);
                bw = readlane64(bw, 63);
                const int wc = 511 - (int)(bw & 511);
                nk = ((bw >> 9) << 32) | rowf | (u32)wc;
            }
        }

        // ---- merged key write into (rstar) owner slot ----
        {
            const int rl = rstar & 63, rj = rstar >> 6;
            const bool mine = (lane == rl);
            k0 = (mine && rj == 0) ? nk : k0;  k1 = (mine && rj == 1) ? nk : k1;
            k2 = (mine && rj == 2) ? nk : k2;  k3 = (mine && rj == 3) ? nk : k3;
            k4 = (mine && rj == 4) ? nk : k4;  k5 = (mine && rj == 5) ? nk : k5;
            k6 = (mine && rj == 6) ? nk : k6;  k7 = (mine && rj == 7) ? nk : k7;
        }

        done += valid ? 1 : 0;
        if (done >= NN) break;
    }
}

extern "C" void kernel_launch(void* const* d_in, const int* in_sizes, int n_in,
                              void* d_out, int out_size, void* d_ws, size_t ws_size,
                              hipStream_t stream) {
    const float* s = (const float*)d_in[0];
    float* out = (float*)d_out;

    build_top<<<dim3(BATCH * NN / 4), dim3(256), 0, stream>>>(s, out);
    greedy_match<<<dim3(BATCH), dim3(64), 0, stream>>>(s, out);
}